// Round 3
// baseline (3758.017 us; speedup 1.0000x reference)
//
#include <hip/hip_runtime.h>
#include <cstddef>

#define DEV static __device__ __forceinline__

constexpr int B_TOTAL = 32768;
constexpr int ROWS = 64;               // batch rows per block
constexpr int NBLK = B_TOTAL / ROWS;   // 512 per tower

// Transposed-weight layout per tower (floats):
//   TW0[75][100] @0, TW1[35][40] @7500, TW2[14][16] @8900,
//   b0'[100] @9124, b1'[40] @9224, b2'[16] @9264  -> total 9280
// k' = unit*4 + gate (0=i,1=f,2=g,3=o): one unit's 4 gate weights = one float4.
constexpr int TW1_OFF = 7500, TW2_OFF = 8900;
constexpr int BP0_OFF = 9124, BP1_OFF = 9224, BP2_OFF = 9264;
constexpr int TOW_FLOATS = 9280;
constexpr int HQ_OFF = 2 * TOW_FLOATS;
constexpr int HP_OFF = HQ_OFF + B_TOTAL * 4;

DEV float fexp2(float x) { return __builtin_amdgcn_exp2f(x); }
DEV float frcp(float x) { return __builtin_amdgcn_rcpf(x); }
DEV float fsig(float x) { return frcp(1.0f + fexp2(-1.4426950408889634f * x)); }
DEV float ftanh_(float x) { return 2.0f * frcp(1.0f + fexp2(-2.8853900817779268f * x)) - 1.0f; }

// ---------------- prep: transpose + gate-interleave weights into ws ----------
__global__ __launch_bounds__(256) void prep_weights(
    const float* __restrict__ qWih0, const float* __restrict__ qWhh0, const float* __restrict__ qb0,
    const float* __restrict__ qWih1, const float* __restrict__ qWhh1, const float* __restrict__ qb1,
    const float* __restrict__ qWih2, const float* __restrict__ qWhh2, const float* __restrict__ qb2,
    const float* __restrict__ pWih0, const float* __restrict__ pWhh0, const float* __restrict__ pb0,
    const float* __restrict__ pWih1, const float* __restrict__ pWhh1, const float* __restrict__ pb1,
    const float* __restrict__ pWih2, const float* __restrict__ pWhh2, const float* __restrict__ pb2,
    float* __restrict__ ws) {
  const bool isp = (blockIdx.x == 1);
  const float* Wih0 = isp ? pWih0 : qWih0; const float* Whh0 = isp ? pWhh0 : qWhh0;
  const float* b0   = isp ? pb0   : qb0;
  const float* Wih1 = isp ? pWih1 : qWih1; const float* Whh1 = isp ? pWhh1 : qWhh1;
  const float* b1   = isp ? pb1   : qb1;
  const float* Wih2 = isp ? pWih2 : qWih2; const float* Whh2 = isp ? pWhh2 : qWhh2;
  const float* b2   = isp ? pb2   : qb2;
  float* out = ws + (isp ? TOW_FLOATS : 0);

  for (int e = threadIdx.x; e < TOW_FLOATS; e += 256) {
    float v;
    if (e < TW1_OFF) {
      const int j = e / 100, k = e % 100, u = k >> 2, gt = k & 3;
      const int rr = gt * 25 + u;
      v = (j < 50) ? Wih0[rr * 50 + j] : Whh0[rr * 25 + (j - 50)];
    } else if (e < TW2_OFF) {
      const int i = e - TW1_OFF, j = i / 40, k = i % 40, u = k >> 2, gt = k & 3;
      const int rr = gt * 10 + u;
      v = (j < 25) ? Wih1[rr * 25 + j] : Whh1[rr * 10 + (j - 25)];
    } else if (e < BP0_OFF) {
      const int i = e - TW2_OFF, j = i / 16, k = i % 16, u = k >> 2, gt = k & 3;
      const int rr = gt * 4 + u;
      v = (j < 10) ? Wih2[rr * 10 + j] : Whh2[rr * 4 + (j - 10)];
    } else if (e < BP1_OFF) {
      const int k = e - BP0_OFF, u = k >> 2, gt = k & 3; v = b0[gt * 25 + u];
    } else if (e < BP2_OFF) {
      const int k = e - BP1_OFF, u = k >> 2, gt = k & 3; v = b1[gt * 10 + u];
    } else {
      const int k = e - BP2_OFF, u = k >> 2, gt = k & 3; v = b2[gt * 4 + u];
    }
    out[e] = v;
  }
}

// --------------- one layer timestep, NU units of this wave -------------------
template <int DIN, int H, int NU>
DEV void layer_step(const float* __restrict__ tw, const float* __restrict__ bp,
                    const float* __restrict__ xin, const int xstr,
                    const float* __restrict__ hprev, const int hstr,
                    float* __restrict__ hcur,
                    const int u0, float* __restrict__ c, const int r) {
  float g[4 * NU];
#pragma unroll
  for (int k = 0; k < 4 * NU; ++k) g[k] = bp[4 * u0 + k];

#pragma unroll 5
  for (int j = 0; j < DIN; ++j) {
    const float v = xin[r * xstr + j];
    const float4* __restrict__ w = reinterpret_cast<const float4*>(tw + j * 4 * H) + u0;
#pragma unroll
    for (int u = 0; u < NU; ++u) {
      const float4 wv = w[u];
      g[4 * u + 0] = fmaf(wv.x, v, g[4 * u + 0]);
      g[4 * u + 1] = fmaf(wv.y, v, g[4 * u + 1]);
      g[4 * u + 2] = fmaf(wv.z, v, g[4 * u + 2]);
      g[4 * u + 3] = fmaf(wv.w, v, g[4 * u + 3]);
    }
  }
#pragma unroll 5
  for (int j = 0; j < H; ++j) {
    const float v = hprev[r * hstr + j];
    const float4* __restrict__ w = reinterpret_cast<const float4*>(tw + (DIN + j) * 4 * H) + u0;
#pragma unroll
    for (int u = 0; u < NU; ++u) {
      const float4 wv = w[u];
      g[4 * u + 0] = fmaf(wv.x, v, g[4 * u + 0]);
      g[4 * u + 1] = fmaf(wv.y, v, g[4 * u + 1]);
      g[4 * u + 2] = fmaf(wv.z, v, g[4 * u + 2]);
      g[4 * u + 3] = fmaf(wv.w, v, g[4 * u + 3]);
    }
  }
#pragma unroll
  for (int u = 0; u < NU; ++u) {
    const float gi = fsig(g[4 * u + 0]);
    const float gf = fsig(g[4 * u + 1]);
    const float gg = ftanh_(g[4 * u + 2]);
    const float go = fsig(g[4 * u + 3]);
    const float cn = fmaf(gf, c[u], gi * gg);
    c[u] = cn;
    hcur[r * hstr + u0 + u] = go * ftanh_(cn);
  }
}

// even blocks -> p tower (T=50), odd -> q tower (T=12); interleaved for tail.
// 256 threads = 4 waves; unit splits L0 {7,6,6,6}, L1 {3,3,2,2}, L2 {1,1,1,1}.
__global__ __launch_bounds__(256, 1) void lstm_towers(const float* __restrict__ q,
                                                      const float* __restrict__ p,
                                                      float* __restrict__ ws) {
  __shared__ float xb[64 * 51];        // stride 51 (odd -> 2-way max, free)
  __shared__ float h0b[2][64 * 25];    // stride 25
  __shared__ float h1b[2][64 * 11];    // stride 11
  __shared__ float h2b[2][64 * 5];     // stride 5

  const int bid = blockIdx.x;
  const bool isp = (bid & 1) == 0;
  const int row0 = (bid >> 1) * ROWS;
  const int T = isp ? 50 : 12;
  const float* __restrict__ x = isp ? p : q;
  const float* __restrict__ tw = ws + (isp ? TOW_FLOATS : 0);
  float* __restrict__ hout_g = ws + (isp ? HP_OFF : HQ_OFF);

  const int tid = threadIdx.x;
  const int r = tid & 63;
  const int wid = tid >> 6;
  // force wave-uniform unit offsets -> scalar (s_load) weight fetches
  const int u0L0 = __builtin_amdgcn_readfirstlane(wid == 0 ? 0 : 7 + (wid - 1) * 6);
  const int u0L1 = __builtin_amdgcn_readfirstlane(wid < 2 ? 3 * wid : 6 + 2 * (wid - 2));
  const int u0L2 = __builtin_amdgcn_readfirstlane(wid);

  const float* tw0 = tw;            const float* bp0 = tw + BP0_OFF;
  const float* tw1 = tw + TW1_OFF;  const float* bp1 = tw + BP1_OFF;
  const float* tw2 = tw + TW2_OFF;  const float* bp2 = tw + BP2_OFF;

  // per-thread x staging slots: 1600 float2 per step, <=7 per thread
  const float* gp[7]; int la[7]; bool av[7];
#pragma unroll
  for (int k = 0; k < 7; ++k) {
    const int i = tid + 256 * k;
    av[k] = (i < 1600);
    const int ii = av[k] ? i : 0;
    const int rr = ii / 25, j2 = ii % 25;
    gp[k] = x + ((size_t)(row0 + rr) * T) * 50 + 2 * j2;
    la[k] = rr * 51 + 2 * j2;
  }

  // zero-init prev-state buffers (buffer 0; first reads at t=0 use rb=0)
  for (int i = tid; i < 64 * 25; i += 256) h0b[0][i] = 0.0f;
  for (int i = tid; i < 64 * 11; i += 256) h1b[0][i] = 0.0f;
  for (int i = tid; i < 64 * 5; i += 256) h2b[0][i] = 0.0f;

  float2 xr[7];
#pragma unroll
  for (int k = 0; k < 7; ++k)
    if (av[k]) xr[k] = *reinterpret_cast<const float2*>(gp[k]);

  float c0[7] = {}, c1[3] = {}, c2[1] = {};

  for (int t = 0; t < T; ++t) {
    // stage x_t (regs -> LDS)
#pragma unroll
    for (int k = 0; k < 7; ++k)
      if (av[k]) { xb[la[k]] = xr[k].x; xb[la[k] + 1] = xr[k].y; }
    __syncthreads();  // barrier 1: xb ready, all h_{t-1} writes visible

    // prefetch x_{t+1}; latency hides under the L0 phase
    if (t + 1 < T) {
#pragma unroll
      for (int k = 0; k < 7; ++k)
        if (av[k]) xr[k] = *reinterpret_cast<const float2*>(gp[k] + (t + 1) * 50);
    }

    const int rb = t & 1, wb = rb ^ 1;
    const float* h0p = h0b[rb]; float* h0c = h0b[wb];
    const float* h1p = h1b[rb]; float* h1c = h1b[wb];
    const float* h2p = h2b[rb]; float* h2c = h2b[wb];

    if (wid == 0) layer_step<50, 25, 7>(tw0, bp0, xb, 51, h0p, 25, h0c, u0L0, c0, r);
    else          layer_step<50, 25, 6>(tw0, bp0, xb, 51, h0p, 25, h0c, u0L0, c0, r);
    __syncthreads();  // barrier 2: h0_t visible

    if (wid < 2) layer_step<25, 10, 3>(tw1, bp1, h0c, 25, h1p, 11, h1c, u0L1, c1, r);
    else         layer_step<25, 10, 2>(tw1, bp1, h0c, 25, h1p, 11, h1c, u0L1, c1, r);
    __syncthreads();  // barrier 3: h1_t visible

    layer_step<10, 4, 1>(tw2, bp2, h1c, 11, h2p, 5, h2c, u0L2, c2, r);
    // no barrier: next phase only overwrites xb (nobody reads it until after
    // barrier 1) and h2c readers are separated by barriers 1-3 of t+1.
  }
  __syncthreads();  // final h2 (buffer 0 for both T=50 and T=12) visible

  if (tid < 64) {
    const float4 o = make_float4(h2b[0][r * 5 + 0], h2b[0][r * 5 + 1],
                                 h2b[0][r * 5 + 2], h2b[0][r * 5 + 3]);
    reinterpret_cast<float4*>(hout_g)[row0 + r] = o;
  }
}

// ---------------- head: softmax((hq*hp) @ fW^T + fb) -------------------------
__global__ __launch_bounds__(256) void combine_head(
    const float* __restrict__ hq, const float* __restrict__ hp,
    const float* __restrict__ fW, const float* __restrict__ fb,
    float* __restrict__ out) {
  const int b = blockIdx.x * blockDim.x + (int)threadIdx.x;
  if (b >= B_TOTAL) return;
  const float4 vq = reinterpret_cast<const float4*>(hq)[b];
  const float4 vp = reinterpret_cast<const float4*>(hp)[b];
  const float s0 = vq.x * vp.x, s1 = vq.y * vp.y, s2 = vq.z * vp.z, s3 = vq.w * vp.w;
  float l0 = fb[0], l1 = fb[1];
  l0 = fmaf(s0, fW[0], l0); l0 = fmaf(s1, fW[1], l0); l0 = fmaf(s2, fW[2], l0); l0 = fmaf(s3, fW[3], l0);
  l1 = fmaf(s0, fW[4], l1); l1 = fmaf(s1, fW[5], l1); l1 = fmaf(s2, fW[6], l1); l1 = fmaf(s3, fW[7], l1);
  const float m = fmaxf(l0, l1);
  const float e0 = fexp2(1.4426950408889634f * (l0 - m));
  const float e1 = fexp2(1.4426950408889634f * (l1 - m));
  const float inv = frcp(e0 + e1);
  reinterpret_cast<float2*>(out)[b] = make_float2(e0 * inv, e1 * inv);
}

extern "C" void kernel_launch(void* const* d_in, const int* in_sizes, int n_in,
                              void* d_out, int out_size, void* d_ws, size_t ws_size,
                              hipStream_t stream) {
  const float* q = (const float*)d_in[0];
  const float* p = (const float*)d_in[1];
  float* ws = (float*)d_ws;

  prep_weights<<<2, 256, 0, stream>>>(
      (const float*)d_in[2], (const float*)d_in[3], (const float*)d_in[4],
      (const float*)d_in[5], (const float*)d_in[6], (const float*)d_in[7],
      (const float*)d_in[8], (const float*)d_in[9], (const float*)d_in[10],
      (const float*)d_in[11], (const float*)d_in[12], (const float*)d_in[13],
      (const float*)d_in[14], (const float*)d_in[15], (const float*)d_in[16],
      (const float*)d_in[17], (const float*)d_in[18], (const float*)d_in[19],
      ws);

  lstm_towers<<<2 * NBLK, 256, 0, stream>>>(q, p, ws);

  combine_head<<<B_TOTAL / 256, 256, 0, stream>>>(
      ws + HQ_OFF, ws + HP_OFF,
      (const float*)d_in[20], (const float*)d_in[21], (float*)d_out);
}